// Round 2
// baseline (757.226 us; speedup 1.0000x reference)
//
#include <hip/hip_runtime.h>

#define Bsz 8
#define Nn  512
#define Dd  768
#define Ll  16

// ws layout: At [B*L*N floats] | Bt [B*L*N floats] | acc[8]
// acc idx: 0=tp(u32) 1=tn(u32) 2=fp(u32) 3=valc(u32) 4=span_num(f32) 5=se_sum(f32)

// ---------------------------------------------------------------------------
// Kernel 1: per 8-row group of x, compute all 64 dot products (32 se cols,
// 16 a-cols, 16 bb-cols), do the start/end focal loss inline, store At/Bt
// transposed to [ (b*L+l)*N + n ] for coalesced reads in kernel 2.
// ---------------------------------------------------------------------------
__global__ __launch_bounds__(256) void k_prep(
    const float* __restrict__ x, const float* __restrict__ start,
    const float* __restrict__ end, const int* __restrict__ seqlen,
    const float* __restrict__ W_se, const float* __restrict__ b_se,
    const float* __restrict__ W_span, const float* __restrict__ b_span,
    float* __restrict__ At, float* __restrict__ Bt, float* __restrict__ acc)
{
    __shared__ float xs[8 * Dd];        // 24 KB
    __shared__ float part[256 * 8];     // 8 KB
    __shared__ float s_se;

    const int tid = threadIdx.x;
    const int blk = blockIdx.x;         // 512 blocks: b*64 + group
    const int b   = blk >> 6;
    const int n0  = (blk & 63) * 8;

    if (tid == 0) s_se = 0.0f;

    // load 8 rows of x (8*768 floats) via float4
    const float4* xsrc = (const float4*)(x + (size_t)(b * Nn + n0) * Dd);
    float4* xd = (float4*)xs;
    for (int i = tid; i < 8 * Dd / 4; i += 256) xd[i] = xsrc[i];
    __syncthreads();

    const int c = tid & 63;   // column 0..63
    const int q = tid >> 6;   // k-quarter 0..3

    float a8[8];
#pragma unroll
    for (int r = 0; r < 8; ++r) a8[r] = 0.0f;

    const float* w;
    int stride;
    if (c < 32)       { w = W_se + c;                    stride = 32; }
    else if (c < 48)  { w = W_span + (c - 32);           stride = 16; }
    else              { w = W_span + Dd * 16 + (c - 48); stride = 16; }

    const int k0 = q * 192;
    for (int k = k0; k < k0 + 192; ++k) {
        const float wv = w[(size_t)k * stride];
#pragma unroll
        for (int r = 0; r < 8; ++r) a8[r] += xs[r * Dd + k] * wv;
    }
#pragma unroll
    for (int r = 0; r < 8; ++r) part[tid * 8 + r] = a8[r];
    __syncthreads();

    if (tid < 64) {
        float z[8];
#pragma unroll
        for (int r = 0; r < 8; ++r)
            z[r] = part[c * 8 + r] + part[(c + 64) * 8 + r] +
                   part[(c + 128) * 8 + r] + part[(c + 192) * 8 + r];

        if (c < 32) {
            // start/end focal loss, masked by n < seqlen[b]
            // start,end are [B, L, N]: batch stride is Ll*Nn (FIXED: was 2*Ll*Nn OOB)
            const int sl = seqlen[b];
            float lsum = 0.0f;
            const float bse = b_se[c];
#pragma unroll
            for (int r = 0; r < 8; ++r) {
                const int n = n0 + r;
                const float zz = z[r] + bse;
                const float p = 1.0f / (1.0f + __expf(-zz));
                const float y = (c < 16) ? start[(b * Ll + c) * Nn + n]
                                         : end[(b * Ll + (c - 16)) * Nn + n];
                const float fl = (y == 1.0f)
                    ? (-0.5f * (1.0f - p) * (1.0f - p) * __logf(p))
                    : (-0.5f * p * p * __logf(1.0f - p));
                if (n < sl) lsum += fl;
            }
            atomicAdd(&s_se, lsum);
        } else if (c < 48) {
            const int l = c - 32;
            const float bsp = b_span[l];
#pragma unroll
            for (int r = 0; r < 8; ++r)
                At[(b * Ll + l) * Nn + n0 + r] = z[r] + bsp;  // bias folded in
        } else {
            const int l = c - 48;
#pragma unroll
            for (int r = 0; r < 8; ++r)
                Bt[(b * Ll + l) * Nn + n0 + r] = z[r];
        }
    }
    __syncthreads();
    if (tid == 0) atomicAdd(&acc[5], s_se);
}

// ---------------------------------------------------------------------------
// Kernel 2: the big [B,L,N,N] pass. 8192 blocks x 256 threads x 4 float4
// items per thread, all loads issued up-front for MLP. Fast exp/log.
//
// focal closed form: z = logit; t = (span==1)? z : -z; u=e^{-t}; d=1+u;
//   q = sigmoid(t) = 1/d  -> log q = -log d;  m = 1-q = u/d
//   focal = -0.5 * m^2 * log q = 0.5 * (u/d)^2 * log d
// ---------------------------------------------------------------------------
__global__ __launch_bounds__(256) void k_span(
    const float* __restrict__ At, const float* __restrict__ Bt,
    const int* __restrict__ span, const int* __restrict__ val,
    float* __restrict__ out, float* __restrict__ acc)
{
    const int tid = threadIdx.x;
    const int base = blockIdx.x * (256 * 4) + tid;   // item = float4 index

    const int4*  s4 = (const int4*)span;
    const int4*  v4 = (const int4*)val;
    float4*      o4 = (float4*)out;

    int  vid[4];
    int4 sp[4], vv[4];
    float4 bt[4];
    float  av[4];

#pragma unroll
    for (int k = 0; k < 4; ++k) {
        vid[k] = base + k * 256;
        sp[k]  = s4[vid[k]];
        vv[k]  = v4[vid[k]];
        const int ri = vid[k] >> 7;                  // (b*L+l)*N + i
        av[k]  = At[ri];
        bt[k]  = *(const float4*)(Bt + ((ri >> 9) << 9) + ((vid[k] & 127) << 2));
    }

    int tpc = 0, tnc = 0, fpc = 0, vc = 0;
    float ls = 0.0f;

#define DO_ELEM(aa, btj, spv, vvv, pout)                                      \
    {                                                                         \
        const float z = (aa) + (btj);                                         \
        const int pred = (z > 0.0f) ? 1 : 0;                                  \
        (pout) = pred ? 1.0f : 0.0f;                                          \
        tpc += ((spv) == 1) & pred;                                           \
        tnc += ((spv) == 1) & (pred ^ 1);                                     \
        fpc += ((spv) == 0) & ((vvv) == 1) & pred;                            \
        vc  += (vvv);                                                         \
        const float t = ((spv) == 1) ? z : -z;                                \
        const float u = __expf(-t);                                           \
        const float d = 1.0f + u;                                             \
        const float m = u * __builtin_amdgcn_rcpf(d);                         \
        const float fl = 0.5f * m * m * __logf(d);                            \
        ls += (vvv) ? fl : 0.0f;                                              \
    }

#pragma unroll
    for (int k = 0; k < 4; ++k) {
        float4 po;
        DO_ELEM(av[k], bt[k].x, sp[k].x, vv[k].x, po.x)
        DO_ELEM(av[k], bt[k].y, sp[k].y, vv[k].y, po.y)
        DO_ELEM(av[k], bt[k].z, sp[k].z, vv[k].z, po.z)
        DO_ELEM(av[k], bt[k].w, sp[k].w, vv[k].w, po.w)
        o4[vid[k]] = po;
    }
#undef DO_ELEM

    // wave (64-lane) reduction
    for (int off = 32; off; off >>= 1) {
        tpc += __shfl_down(tpc, off);
        tnc += __shfl_down(tnc, off);
        fpc += __shfl_down(fpc, off);
        vc  += __shfl_down(vc,  off);
        ls  += __shfl_down(ls,  off);
    }

    __shared__ int   si[4][4];
    __shared__ float sf[4];
    const int wave = tid >> 6, lane = tid & 63;
    if (lane == 0) {
        si[wave][0] = tpc; si[wave][1] = tnc; si[wave][2] = fpc; si[wave][3] = vc;
        sf[wave] = ls;
    }
    __syncthreads();
    if (tid == 0) {
        int t0 = 0, t1 = 0, t2 = 0, t3 = 0;
        float f = 0.0f;
        for (int w = 0; w < 4; ++w) {
            t0 += si[w][0]; t1 += si[w][1]; t2 += si[w][2]; t3 += si[w][3];
            f += sf[w];
        }
        unsigned int* accU = (unsigned int*)acc;
        atomicAdd(&accU[0], (unsigned int)t0);
        atomicAdd(&accU[1], (unsigned int)t1);
        atomicAdd(&accU[2], (unsigned int)t2);
        atomicAdd(&accU[3], (unsigned int)t3);
        atomicAdd(&acc[4], f);
    }
}

// ---------------------------------------------------------------------------
// Kernel 3: finalize the 5 scalar outputs
// ---------------------------------------------------------------------------
__global__ void k_fin(const float* __restrict__ acc,
                      const int* __restrict__ seqlen,
                      float* __restrict__ out5)
{
    if (threadIdx.x == 0 && blockIdx.x == 0) {
        const unsigned int* accU = (const unsigned int*)acc;
        int ssum = 0;
        for (int i = 0; i < Bsz; ++i) ssum += seqlen[i];
        out5[0] = (float)accU[0];                                   // tp
        out5[1] = (float)accU[1];                                   // tn
        out5[2] = (float)accU[2];                                   // fp
        out5[3] = acc[5] / (2.0f * Ll * (float)ssum);               // startend_loss
        out5[4] = acc[4] / ((float)accU[3] + 1e-6f);                // span_loss
    }
}

extern "C" void kernel_launch(void* const* d_in, const int* in_sizes, int n_in,
                              void* d_out, int out_size, void* d_ws, size_t ws_size,
                              hipStream_t stream) {
    const float* x      = (const float*)d_in[0];
    const float* start  = (const float*)d_in[1];
    const float* end    = (const float*)d_in[2];
    const int*   span   = (const int*)d_in[3];
    const int*   val    = (const int*)d_in[4];
    const int*   seqlen = (const int*)d_in[5];
    const float* W_se   = (const float*)d_in[6];
    const float* b_se   = (const float*)d_in[7];
    const float* W_span = (const float*)d_in[8];
    const float* b_span = (const float*)d_in[9];

    float* out = (float*)d_out;

    const size_t n_at = (size_t)Bsz * Ll * Nn;    // 65536
    float* At  = (float*)d_ws;
    float* Bt  = At + n_at;
    float* acc = Bt + n_at;

    hipMemsetAsync(acc, 0, 8 * sizeof(float), stream);

    k_prep<<<Bsz * (Nn / 8), 256, 0, stream>>>(x, start, end, seqlen,
                                               W_se, b_se, W_span, b_span,
                                               At, Bt, acc);

    // 8,388,608 float4 items = 8192 blocks * 256 threads * 4 items
    const long long total_elems = (long long)Bsz * Ll * Nn * Nn;   // 33554432
    k_span<<<8192, 256, 0, stream>>>(At, Bt, span, val, out, acc);

    k_fin<<<1, 64, 0, stream>>>(acc, seqlen, out + total_elems);
}

// Round 3
// 371.810 us; speedup vs baseline: 2.0366x; 2.0366x over previous
//
#include <hip/hip_runtime.h>

#define Bsz 8
#define Nn  512
#define Dd  768
#define Ll  16

#define SPAN_BLOCKS 2048
#define PREP_BLOCKS (Bsz * (Nn / 8))   // 512

// ws layout (floats): At[65536] | Bt[65536] | se_part[512] | pb[SPAN_BLOCKS*8]
// pb[blk*8 + {0:tp,1:tn,2:fp,3:valc,4:span_loss_sum}]  -- plain stores, NO atomics

// ---------------------------------------------------------------------------
// Kernel 1: per 8-row group of x, compute all 64 dot products (32 se cols,
// 16 a-cols, 16 bb-cols), do the start/end focal loss inline, store At/Bt
// transposed to [ (b*L+l)*N + n ] for coalesced reads in kernel 2.
// ---------------------------------------------------------------------------
__global__ __launch_bounds__(256) void k_prep(
    const float* __restrict__ x, const float* __restrict__ start,
    const float* __restrict__ end, const int* __restrict__ seqlen,
    const float* __restrict__ W_se, const float* __restrict__ b_se,
    const float* __restrict__ W_span, const float* __restrict__ b_span,
    float* __restrict__ At, float* __restrict__ Bt, float* __restrict__ se_part)
{
    __shared__ float xs[8 * Dd];        // 24 KB
    __shared__ float part[256 * 8];     // 8 KB
    __shared__ float s_se;

    const int tid = threadIdx.x;
    const int blk = blockIdx.x;         // 512 blocks: b*64 + group
    const int b   = blk >> 6;
    const int n0  = (blk & 63) * 8;

    if (tid == 0) s_se = 0.0f;

    const float4* xsrc = (const float4*)(x + (size_t)(b * Nn + n0) * Dd);
    float4* xd = (float4*)xs;
    for (int i = tid; i < 8 * Dd / 4; i += 256) xd[i] = xsrc[i];
    __syncthreads();

    const int c = tid & 63;   // column 0..63
    const int q = tid >> 6;   // k-quarter 0..3

    float a8[8];
#pragma unroll
    for (int r = 0; r < 8; ++r) a8[r] = 0.0f;

    const float* w;
    int stride;
    if (c < 32)       { w = W_se + c;                    stride = 32; }
    else if (c < 48)  { w = W_span + (c - 32);           stride = 16; }
    else              { w = W_span + Dd * 16 + (c - 48); stride = 16; }

    const int k0 = q * 192;
    for (int k = k0; k < k0 + 192; ++k) {
        const float wv = w[(size_t)k * stride];
#pragma unroll
        for (int r = 0; r < 8; ++r) a8[r] += xs[r * Dd + k] * wv;
    }
#pragma unroll
    for (int r = 0; r < 8; ++r) part[tid * 8 + r] = a8[r];
    __syncthreads();

    if (tid < 64) {
        float z[8];
#pragma unroll
        for (int r = 0; r < 8; ++r)
            z[r] = part[c * 8 + r] + part[(c + 64) * 8 + r] +
                   part[(c + 128) * 8 + r] + part[(c + 192) * 8 + r];

        if (c < 32) {
            // start,end are [B, L, N]: batch stride Ll*Nn
            const int sl = seqlen[b];
            float lsum = 0.0f;
            const float bse = b_se[c];
#pragma unroll
            for (int r = 0; r < 8; ++r) {
                const int n = n0 + r;
                const float zz = z[r] + bse;
                const float p = 1.0f / (1.0f + __expf(-zz));
                const float y = (c < 16) ? start[(b * Ll + c) * Nn + n]
                                         : end[(b * Ll + (c - 16)) * Nn + n];
                const float fl = (y == 1.0f)
                    ? (-0.5f * (1.0f - p) * (1.0f - p) * __logf(p))
                    : (-0.5f * p * p * __logf(1.0f - p));
                if (n < sl) lsum += fl;
            }
            atomicAdd(&s_se, lsum);   // LDS atomic, 32 per block — cheap
        } else if (c < 48) {
            const int l = c - 32;
            const float bsp = b_span[l];
#pragma unroll
            for (int r = 0; r < 8; ++r)
                At[(b * Ll + l) * Nn + n0 + r] = z[r] + bsp;  // bias folded in
        } else {
            const int l = c - 48;
#pragma unroll
            for (int r = 0; r < 8; ++r)
                Bt[(b * Ll + l) * Nn + n0 + r] = z[r];
        }
    }
    __syncthreads();
    if (tid == 0) se_part[blk] = s_se;   // plain store, distinct address per block
}

// ---------------------------------------------------------------------------
// Kernel 2: the big [B,L,N,N] pass. 2048 blocks x 256 threads x 16 float4
// items (4 batches of 4, 12 loads in flight per batch). NO global atomics:
// per-block partials to pb[blk*8..].
//
// focal closed form: z = logit; t = (span==1)? z : -z; u=e^{-t}; d=1+u;
//   focal = 0.5 * (u/d)^2 * log d
// ---------------------------------------------------------------------------
__global__ __launch_bounds__(256) void k_span(
    const float* __restrict__ At, const float* __restrict__ Bt,
    const int* __restrict__ span, const int* __restrict__ val,
    float* __restrict__ out, float* __restrict__ pb)
{
    const int tid = threadIdx.x;
    const int base0 = blockIdx.x * (256 * 16) + tid;   // float4-item index

    const int4*  s4 = (const int4*)span;
    const int4*  v4 = (const int4*)val;
    float4*      o4 = (float4*)out;

    int tpc = 0, tnc = 0, fpc = 0, vc = 0;
    float ls = 0.0f;

#define DO_ELEM(aa, btj, spv, vvv, pout)                                      \
    {                                                                         \
        const float z = (aa) + (btj);                                         \
        const int pred = (z > 0.0f) ? 1 : 0;                                  \
        (pout) = pred ? 1.0f : 0.0f;                                          \
        tpc += ((spv) == 1) & pred;                                           \
        tnc += ((spv) == 1) & (pred ^ 1);                                     \
        fpc += ((spv) == 0) & ((vvv) == 1) & pred;                            \
        vc  += (vvv);                                                         \
        const float t = ((spv) == 1) ? z : -z;                                \
        const float u = __expf(-t);                                           \
        const float d = 1.0f + u;                                             \
        const float m = u * __builtin_amdgcn_rcpf(d);                         \
        const float fl = 0.5f * m * m * __logf(d);                            \
        ls += (vvv) ? fl : 0.0f;                                              \
    }

#pragma unroll
    for (int bat = 0; bat < 4; ++bat) {
        int  vid[4];
        int4 sp[4], vv[4];
        float4 bt[4];
        float  av[4];
#pragma unroll
        for (int k = 0; k < 4; ++k) {
            vid[k] = base0 + bat * 1024 + k * 256;
            sp[k]  = s4[vid[k]];
            vv[k]  = v4[vid[k]];
            const int ri = vid[k] >> 7;                  // (b*L+l)*N + i
            av[k]  = At[ri];
            bt[k]  = *(const float4*)(Bt + ((ri >> 9) << 9) + ((vid[k] & 127) << 2));
        }
#pragma unroll
        for (int k = 0; k < 4; ++k) {
            float4 po;
            DO_ELEM(av[k], bt[k].x, sp[k].x, vv[k].x, po.x)
            DO_ELEM(av[k], bt[k].y, sp[k].y, vv[k].y, po.y)
            DO_ELEM(av[k], bt[k].z, sp[k].z, vv[k].z, po.z)
            DO_ELEM(av[k], bt[k].w, sp[k].w, vv[k].w, po.w)
            o4[vid[k]] = po;
        }
    }
#undef DO_ELEM

    // wave (64-lane) reduction
    for (int off = 32; off; off >>= 1) {
        tpc += __shfl_down(tpc, off);
        tnc += __shfl_down(tnc, off);
        fpc += __shfl_down(fpc, off);
        vc  += __shfl_down(vc,  off);
        ls  += __shfl_down(ls,  off);
    }

    __shared__ int   si[4][4];
    __shared__ float sf[4];
    const int wave = tid >> 6, lane = tid & 63;
    if (lane == 0) {
        si[wave][0] = tpc; si[wave][1] = tnc; si[wave][2] = fpc; si[wave][3] = vc;
        sf[wave] = ls;
    }
    __syncthreads();
    if (tid == 0) {
        int t0 = 0, t1 = 0, t2 = 0, t3 = 0;
        float f = 0.0f;
        for (int w = 0; w < 4; ++w) {
            t0 += si[w][0]; t1 += si[w][1]; t2 += si[w][2]; t3 += si[w][3];
            f += sf[w];
        }
        float* dst = pb + blockIdx.x * 8;
        dst[0] = (float)t0;   // counts <= 16384/block: exact in float
        dst[1] = (float)t1;
        dst[2] = (float)t2;
        dst[3] = (float)t3;
        dst[4] = f;
    }
}

// ---------------------------------------------------------------------------
// Kernel 3: reduce per-block partials and finalize the 5 scalar outputs
// ---------------------------------------------------------------------------
__global__ __launch_bounds__(256) void k_fin(
    const float* __restrict__ pb, const float* __restrict__ se_part,
    const int* __restrict__ seqlen, float* __restrict__ out5)
{
    const int tid = threadIdx.x;
    long long t0 = 0, t1 = 0, t2 = 0, t3 = 0;   // int accumulation: exact
    float f = 0.0f, se = 0.0f;

    for (int i = tid; i < SPAN_BLOCKS; i += 256) {
        const float4 p0 = *(const float4*)(pb + i * 8);
        const float  p4 = pb[i * 8 + 4];
        t0 += (long long)p0.x; t1 += (long long)p0.y;
        t2 += (long long)p0.z; t3 += (long long)p0.w;
        f  += p4;
    }
    for (int i = tid; i < PREP_BLOCKS; i += 256) se += se_part[i];

    // wave reduce
    for (int off = 32; off; off >>= 1) {
        t0 += __shfl_down(t0, off);
        t1 += __shfl_down(t1, off);
        t2 += __shfl_down(t2, off);
        t3 += __shfl_down(t3, off);
        f  += __shfl_down(f,  off);
        se += __shfl_down(se, off);
    }

    __shared__ long long sl[4][4];
    __shared__ float sfl[4][2];
    const int wave = tid >> 6, lane = tid & 63;
    if (lane == 0) {
        sl[wave][0] = t0; sl[wave][1] = t1; sl[wave][2] = t2; sl[wave][3] = t3;
        sfl[wave][0] = f; sfl[wave][1] = se;
    }
    __syncthreads();
    if (tid == 0) {
        long long a0 = 0, a1 = 0, a2 = 0, a3 = 0;
        float af = 0.0f, ase = 0.0f;
        for (int w = 0; w < 4; ++w) {
            a0 += sl[w][0]; a1 += sl[w][1]; a2 += sl[w][2]; a3 += sl[w][3];
            af += sfl[w][0]; ase += sfl[w][1];
        }
        int ssum = 0;
        for (int i = 0; i < Bsz; ++i) ssum += seqlen[i];
        out5[0] = (float)a0;                                   // tp
        out5[1] = (float)a1;                                   // tn
        out5[2] = (float)a2;                                   // fp
        out5[3] = ase / (2.0f * Ll * (float)ssum);             // startend_loss
        out5[4] = af / ((float)a3 + 1e-6f);                    // span_loss
    }
}

extern "C" void kernel_launch(void* const* d_in, const int* in_sizes, int n_in,
                              void* d_out, int out_size, void* d_ws, size_t ws_size,
                              hipStream_t stream) {
    const float* x      = (const float*)d_in[0];
    const float* start  = (const float*)d_in[1];
    const float* end    = (const float*)d_in[2];
    const int*   span   = (const int*)d_in[3];
    const int*   val    = (const int*)d_in[4];
    const int*   seqlen = (const int*)d_in[5];
    const float* W_se   = (const float*)d_in[6];
    const float* b_se   = (const float*)d_in[7];
    const float* W_span = (const float*)d_in[8];
    const float* b_span = (const float*)d_in[9];

    float* out = (float*)d_out;

    const size_t n_at = (size_t)Bsz * Ll * Nn;    // 65536
    float* At      = (float*)d_ws;
    float* Bt      = At + n_at;
    float* se_part = Bt + n_at;
    float* pb      = se_part + PREP_BLOCKS;

    k_prep<<<PREP_BLOCKS, 256, 0, stream>>>(x, start, end, seqlen,
                                            W_se, b_se, W_span, b_span,
                                            At, Bt, se_part);

    const long long total_elems = (long long)Bsz * Ll * Nn * Nn;   // 33554432
    k_span<<<SPAN_BLOCKS, 256, 0, stream>>>(At, Bt, span, val, out, pb);

    k_fin<<<1, 256, 0, stream>>>(pb, se_part, seqlen, out + total_elems);
}